// Round 14
// baseline (239.744 us; speedup 1.0000x reference)
//
#include <hip/hip_runtime.h>

#define NTYPES 5
#define EPB 4096      // edges per hist/scatter block -> 245 blocks at e=1M
#define BKSH 7        // coarse scatter bucket = 128 dsts (nbk=782)
#define BKDST 128
#define SUBD 32       // agg2 sub-bucket = 32 dsts
#define CAP 1024      // max records per 32-dst sub-bucket in LDS (avg 320)

typedef _Float16 half8 __attribute__((ext_vector_type(8)));
typedef _Float16 half4v __attribute__((ext_vector_type(4)));
typedef float float4v __attribute__((ext_vector_type(4)));

// stage rows x 128 f32 tile -> f16 LDS, row stride 256 B, swizzle byte ^= (row&7)<<4
__device__ __forceinline__ void stage_f32(
    _Float16* lds, const float* __restrict__ g, int rows, int stride4, int off4,
    int grow0, int nmax, int t)
{
  const float4* g4 = (const float4*)g;
  for (int i = t; i < rows * 32; i += 256) {
    int row = i >> 5, q = i & 31;
    float4 v = make_float4(0.f, 0.f, 0.f, 0.f);
    int gr = grow0 + row;
    if (gr < nmax) v = g4[(size_t)gr * stride4 + off4 + q];
    half4v hv = { (_Float16)v.x, (_Float16)v.y, (_Float16)v.z, (_Float16)v.w };
    int byte = row * 256 + ((q * 8) ^ ((row & 7) << 4));
    *(half4v*)((char*)lds + byte) = hv;
  }
}

__device__ __forceinline__ half8 frag_ld(const _Float16* lds, int row, int khw) {
  int byte = row * 256 + ((khw * 2) ^ ((row & 7) << 4));
  return *(const half8*)((const char*)lds + byte);
}

__device__ __forceinline__ half8 cvt8(float4 v0, float4 v1) {
  half8 a;
  a[0] = (_Float16)v0.x; a[1] = (_Float16)v0.y; a[2] = (_Float16)v0.z; a[3] = (_Float16)v0.w;
  a[4] = (_Float16)v1.x; a[5] = (_Float16)v1.y; a[6] = (_Float16)v1.z; a[7] = (_Float16)v1.w;
  return a;
}

// nfl(f16) = nh @ Wnf^T ; nh16 = (f16)nh. Full 128-col W in LDS (32 KB),
// batched A loads, no attn epilogue. launch_bounds caps VGPR for occupancy.
__global__ __launch_bounds__(256, 5) void k_gemm0(
    const float* __restrict__ nh, const float* __restrict__ Wnf,
    _Float16* __restrict__ nfl, _Float16* __restrict__ nh16, int n)
{
  __shared__ _Float16 wh[128 * 128];
  const int t = threadIdx.x, lane = t & 63, wv = t >> 6;
  const int r16 = lane & 15, g = lane >> 4;
  stage_f32(wh, Wnf, 128, 32, 0, 0, 1 << 30, t);
  __syncthreads();
  const int nchunk = (n + 63) >> 6;
  for (int c = blockIdx.x; c < nchunk; c += gridDim.x) {
    const int base = c << 6;
    const int arow = base + wv * 16 + r16;
    const bool ok = arow < n;
    const float4* nh4 = (const float4*)(nh + (size_t)arow * 128);
    const float4 z = make_float4(0.f, 0.f, 0.f, 0.f);
    float4 av[8];
    #pragma unroll
    for (int s = 0; s < 4; ++s) {
      av[2 * s]     = ok ? nh4[s * 8 + g * 2]     : z;
      av[2 * s + 1] = ok ? nh4[s * 8 + g * 2 + 1] : z;
    }
    float4v acc[8];
    #pragma unroll
    for (int nf = 0; nf < 8; ++nf) acc[nf] = (float4v){0.f, 0.f, 0.f, 0.f};
    #pragma unroll
    for (int s = 0; s < 4; ++s) {
      half8 a = cvt8(av[2 * s], av[2 * s + 1]);
      if (ok) *(half8*)(nh16 + (size_t)arow * 128 + s * 32 + g * 8) = a;
      #pragma unroll
      for (int nf = 0; nf < 8; ++nf)
        acc[nf] = __builtin_amdgcn_mfma_f32_16x16x32_f16(a, frag_ld(wh, nf * 16 + r16, s * 32 + g * 8), acc[nf], 0, 0, 0);
    }
    #pragma unroll
    for (int rr = 0; rr < 4; ++rr) {
      int node = base + wv * 16 + g * 4 + rr;
      if (node >= n) continue;
      size_t ro = (size_t)node * 128;
      #pragma unroll
      for (int nf = 0; nf < 8; ++nf) nfl[ro + nf * 16 + r16] = (_Float16)acc[nf][rr];
    }
  }
}

// s_src/s_dst = nfl16 @ a_src/a_dst : 16 lanes per node, shuffle-reduce
__global__ __launch_bounds__(256) void k_attn(
    const _Float16* __restrict__ nfl, const float* __restrict__ Wattn,
    float* __restrict__ s_src, float* __restrict__ s_dst, int n)
{
  const int grp = threadIdx.x >> 4, l = threadIdx.x & 15;
  const int node = blockIdx.x * 16 + grp;
  float4 wa0 = *(const float4*)(Wattn + l * 8);
  float4 wa1 = *(const float4*)(Wattn + l * 8 + 4);
  float4 wd0 = *(const float4*)(Wattn + 128 + l * 8);
  float4 wd1 = *(const float4*)(Wattn + 128 + l * 8 + 4);
  if (node >= n) return;
  half8 x = *(const half8*)(nfl + (size_t)node * 128 + l * 8);
  float ss = (float)x[0]*wa0.x + (float)x[1]*wa0.y + (float)x[2]*wa0.z + (float)x[3]*wa0.w
           + (float)x[4]*wa1.x + (float)x[5]*wa1.y + (float)x[6]*wa1.z + (float)x[7]*wa1.w;
  float sd = (float)x[0]*wd0.x + (float)x[1]*wd0.y + (float)x[2]*wd0.z + (float)x[3]*wd0.w
           + (float)x[4]*wd1.x + (float)x[5]*wd1.y + (float)x[6]*wd1.z + (float)x[7]*wd1.w;
  #pragma unroll
  for (int m = 1; m <= 8; m <<= 1) {
    ss += __shfl_xor(ss, m);
    sd += __shfl_xor(sd, m);
  }
  if (l == 0) { s_src[node] = ss; s_dst[node] = sd; }
}

// per-block coarse-bucket histogram (bucket = dst >> BKSH), LDS atomics only
__global__ __launch_bounds__(256) void k_hist(
    const int* __restrict__ dsts, int* __restrict__ cnt, int e, int nbk, int nblk)
{
  __shared__ int hist[1024];
  const int t = threadIdx.x, b = blockIdx.x;
  for (int k = t; k < nbk; k += 256) hist[k] = 0;
  __syncthreads();
  const int i0 = b * EPB;
  const int iend = min(i0 + EPB, e);
  for (int i = i0 + t; i < iend; i += 256)
    atomicAdd(&hist[dsts[i] >> BKSH], 1);
  __syncthreads();
  for (int k = t; k < nbk; k += 256) cnt[k * nblk + b] = hist[k];
}

// ---- exclusive scan (in-place capable), 1024 elems per block ----
__global__ __launch_bounds__(256) void k_scan1(
    const int* __restrict__ deg, int* __restrict__ base, int* __restrict__ bsum, int n)
{
  __shared__ int ws[4];
  int t = threadIdx.x;
  int g0 = blockIdx.x * 1024 + t * 4;
  int4 v = make_int4(0, 0, 0, 0);
  if (g0 + 3 < n) v = *(const int4*)(deg + g0);
  else {
    if (g0     < n) v.x = deg[g0];
    if (g0 + 1 < n) v.y = deg[g0 + 1];
    if (g0 + 2 < n) v.z = deg[g0 + 2];
    if (g0 + 3 < n) v.w = deg[g0 + 3];
  }
  int s = v.x + v.y + v.z + v.w;
  int inc = s;
  #pragma unroll
  for (int d = 1; d < 64; d <<= 1) {
    int o = __shfl_up(inc, d);
    if ((t & 63) >= d) inc += o;
  }
  int wid = t >> 6;
  if ((t & 63) == 63) ws[wid] = inc;
  __syncthreads();
  int woff = 0;
  for (int w = 0; w < wid; ++w) woff += ws[w];
  int exc = woff + inc - s;
  if (g0 + 3 < n) {
    *(int4*)(base + g0) = make_int4(exc, exc + v.x, exc + v.x + v.y, exc + v.x + v.y + v.z);
  } else {
    if (g0     < n) base[g0]     = exc;
    if (g0 + 1 < n) base[g0 + 1] = exc + v.x;
    if (g0 + 2 < n) base[g0 + 2] = exc + v.x + v.y;
  }
  if (t == 255) bsum[blockIdx.x] = woff + inc;
}

__global__ __launch_bounds__(256) void k_scan2(
    const int* __restrict__ bsum, int* __restrict__ boff, int nb)
{
  __shared__ int ws[4];
  int t = threadIdx.x;
  int x = t < nb ? bsum[t] : 0;
  int inc = x;
  #pragma unroll
  for (int d = 1; d < 64; d <<= 1) {
    int o = __shfl_up(inc, d);
    if ((t & 63) >= d) inc += o;
  }
  int wid = t >> 6;
  if ((t & 63) == 63) ws[wid] = inc;
  __syncthreads();
  int woff = 0;
  for (int w = 0; w < wid; ++w) woff += ws[w];
  if (t < nb) boff[t] = woff + inc - x;
}

__global__ __launch_bounds__(256) void k_scan3(
    int* __restrict__ base, const int* __restrict__ boff, int n)
{
  int i = blockIdx.x * 256 + threadIdx.x;
  if (i < n) base[i] += boff[i >> 10];
}

// bucket-grouped scatter: payload = src | ty<<17 | (d&127)<<20, LDS cursors
__global__ __launch_bounds__(256) void k_scatter2(
    const int* __restrict__ ei, const int* __restrict__ ey,
    const int* __restrict__ cnt_s, unsigned* __restrict__ rec,
    int e, int nbk, int nblk)
{
  __shared__ int cur[1024];
  const int t = threadIdx.x, b = blockIdx.x;
  for (int k = t; k < nbk; k += 256) cur[k] = cnt_s[k * nblk + b];
  __syncthreads();
  const int i0 = b * EPB;
  const int iend = min(i0 + EPB, e);
  for (int i = i0 + t; i < iend; i += 256) {
    int s = ei[i], d = ei[e + i], ty = ey[i];
    int pos = atomicAdd(&cur[d >> BKSH], 1);
    rec[pos] = (unsigned)s | ((unsigned)ty << 17) | ((unsigned)(d & (BKDST - 1)) << 20);
  }
}

// one block per 32-dst SUB-bucket: filter coarse-bucket records, LDS CSR,
// per-dst softmax + gather aggregate -> h (f16)
__global__ __launch_bounds__(256) void k_agg2(
    const unsigned* __restrict__ rec, const int* __restrict__ cnt_s,
    const float* __restrict__ s_src, const float* __restrict__ s_dst,
    const _Float16* __restrict__ nfl, _Float16* __restrict__ h,
    int n, int e, int nbk, int nblk)
{
  __shared__ unsigned ord[CAP];
  __shared__ float efl[CAP];
  __shared__ int dcnt[SUBD];
  __shared__ int dbase[SUBD + 1];
  __shared__ float sdl[SUBD];
  const int t = threadIdx.x;
  const int sb = blockIdx.x;       // sub-bucket id
  const int d0 = sb << 5;          // first dst
  const int ndst = min(SUBD, n - d0);
  const int k = sb >> 2;           // coarse bucket (128 dsts)
  const int sub = sb & 3;
  const int bs = cnt_s[k * nblk];
  const int be = (k + 1 < nbk) ? cnt_s[(k + 1) * nblk] : e;
  const int cnt = be - bs;
  if (t < SUBD) {
    dcnt[t] = 0;
    if (t < ndst) sdl[t] = s_dst[d0 + t];
  }
  __syncthreads();
  const int g = t >> 4, l = t & 15;

  // count pass (filtered to this sub-bucket)
  for (int i = t; i < cnt; i += 256) {
    int dl = (rec[bs + i] >> 20) & 127;
    if ((dl >> 5) == sub) atomicAdd(&dcnt[dl & 31], 1);
  }
  __syncthreads();
  if (t < SUBD) {  // single-wave exclusive scan dcnt -> dbase (+cursor seed)
    int v = dcnt[t];
    int inc = v;
    #pragma unroll
    for (int dd = 1; dd < SUBD; dd <<= 1) {
      int o = __shfl_up(inc, dd);
      if (t >= dd) inc += o;
    }
    dbase[t] = inc - v;
    dcnt[t]  = inc - v;
    if (t == SUBD - 1) dbase[SUBD] = inc;
  }
  __syncthreads();
  const int total = dbase[SUBD];

  if (total <= CAP) {
    for (int i = t; i < cnt; i += 256) {
      unsigned p = rec[bs + i];
      int dl = (p >> 20) & 127;
      if ((dl >> 5) == sub) {
        int pos = atomicAdd(&dcnt[dl & 31], 1);
        ord[pos] = p;
      }
    }
    __syncthreads();
    for (int i = t; i < total; i += 256) {
      unsigned p = ord[i];
      float ef = s_src[p & 0x1FFFF] + sdl[(p >> 20) & 31];
      efl[i] = ef >= 0.f ? ef : 0.2f * ef;
    }
    __syncthreads();
    for (int di = g; di < ndst; di += 16) {
      int s0 = dbase[di], deg = dbase[di + 1] - s0;
      float acc[8] = {0.f, 0.f, 0.f, 0.f, 0.f, 0.f, 0.f, 0.f};
      if (deg > 0) {
        float mx[NTYPES];
        #pragma unroll
        for (int tt = 0; tt < NTYPES; ++tt) mx[tt] = -1e30f;
        for (int j0 = 0; j0 < deg; j0 += 16) {
          int jj = j0 + l;
          bool ok = jj < deg;
          float ef = ok ? efl[s0 + jj] : -1e30f;
          int ty = ok ? (int)((ord[s0 + jj] >> 17) & 7) : 7;
          #pragma unroll
          for (int tt = 0; tt < NTYPES; ++tt) {
            float v = (ty == tt) ? ef : -1e30f;
            v = fmaxf(v, __shfl_xor(v, 1)); v = fmaxf(v, __shfl_xor(v, 2));
            v = fmaxf(v, __shfl_xor(v, 4)); v = fmaxf(v, __shfl_xor(v, 8));
            mx[tt] = fmaxf(mx[tt], v);
          }
        }
        float sm[NTYPES];
        #pragma unroll
        for (int tt = 0; tt < NTYPES; ++tt) sm[tt] = 0.f;
        for (int j0 = 0; j0 < deg; j0 += 16) {
          int jj = j0 + l;
          bool ok = jj < deg;
          int ty = ok ? (int)((ord[s0 + jj] >> 17) & 7) : 7;
          float ex = ok ? __expf(efl[s0 + jj] - mx[ty]) : 0.f;
          if (ok) efl[s0 + jj] = ex;
          #pragma unroll
          for (int tt = 0; tt < NTYPES; ++tt) {
            float v = (ty == tt) ? ex : 0.f;
            v += __shfl_xor(v, 1); v += __shfl_xor(v, 2);
            v += __shfl_xor(v, 4); v += __shfl_xor(v, 8);
            sm[tt] += v;
          }
        }
        float rsm[NTYPES];
        #pragma unroll
        for (int tt = 0; tt < NTYPES; ++tt) rsm[tt] = sm[tt] > 0.f ? 1.f / sm[tt] : 0.f;
        int j = 0;
        for (; j + 4 <= deg; j += 4) {
          unsigned p0 = ord[s0 + j],     p1 = ord[s0 + j + 1];
          unsigned p2 = ord[s0 + j + 2], p3 = ord[s0 + j + 3];
          float a0 = efl[s0 + j]     * rsm[(p0 >> 17) & 7];
          float a1 = efl[s0 + j + 1] * rsm[(p1 >> 17) & 7];
          float a2 = efl[s0 + j + 2] * rsm[(p2 >> 17) & 7];
          float a3 = efl[s0 + j + 3] * rsm[(p3 >> 17) & 7];
          half8 x0 = *(const half8*)(nfl + (size_t)(p0 & 0x1FFFF) * 128 + l * 8);
          half8 x1 = *(const half8*)(nfl + (size_t)(p1 & 0x1FFFF) * 128 + l * 8);
          half8 x2 = *(const half8*)(nfl + (size_t)(p2 & 0x1FFFF) * 128 + l * 8);
          half8 x3 = *(const half8*)(nfl + (size_t)(p3 & 0x1FFFF) * 128 + l * 8);
          #pragma unroll
          for (int kk = 0; kk < 8; ++kk) acc[kk] = fmaf(a0, (float)x0[kk], acc[kk]);
          #pragma unroll
          for (int kk = 0; kk < 8; ++kk) acc[kk] = fmaf(a1, (float)x1[kk], acc[kk]);
          #pragma unroll
          for (int kk = 0; kk < 8; ++kk) acc[kk] = fmaf(a2, (float)x2[kk], acc[kk]);
          #pragma unroll
          for (int kk = 0; kk < 8; ++kk) acc[kk] = fmaf(a3, (float)x3[kk], acc[kk]);
        }
        for (; j < deg; ++j) {
          unsigned p0 = ord[s0 + j];
          float a0 = efl[s0 + j] * rsm[(p0 >> 17) & 7];
          half8 x0 = *(const half8*)(nfl + (size_t)(p0 & 0x1FFFF) * 128 + l * 8);
          #pragma unroll
          for (int kk = 0; kk < 8; ++kk) acc[kk] = fmaf(a0, (float)x0[kk], acc[kk]);
        }
      }
      half8 hv;
      #pragma unroll
      for (int kk = 0; kk < 8; ++kk) hv[kk] = (_Float16)acc[kk];
      *(half8*)(h + (size_t)(d0 + di) * 128 + l * 8) = hv;
    }
  } else {
    // fallback (sub-bucket overflow — not expected): stream global coarse range
    const int gb = (t & 63) & 48;
    for (int di = g; di < ndst; di += 16) {
      const int want = sub * SUBD + di;
      float mx[NTYPES], sm[NTYPES];
      #pragma unroll
      for (int tt = 0; tt < NTYPES; ++tt) { mx[tt] = -1e30f; sm[tt] = 0.f; }
      for (int j0 = 0; j0 < cnt; j0 += 16) {
        int jj = j0 + l;
        unsigned p = (jj < cnt) ? rec[bs + jj] : 0xFFFFFFFFu;
        bool mine = (p != 0xFFFFFFFFu) && (int)((p >> 20) & 127) == want;
        float ef = -1e30f; int ty = 7;
        if (mine) {
          ef = s_src[p & 0x1FFFF] + sdl[di];
          ef = ef >= 0.f ? ef : 0.2f * ef;
          ty = (p >> 17) & 7;
        }
        #pragma unroll
        for (int tt = 0; tt < NTYPES; ++tt) {
          float v = (mine && ty == tt) ? ef : -1e30f;
          v = fmaxf(v, __shfl_xor(v, 1)); v = fmaxf(v, __shfl_xor(v, 2));
          v = fmaxf(v, __shfl_xor(v, 4)); v = fmaxf(v, __shfl_xor(v, 8));
          mx[tt] = fmaxf(mx[tt], v);
        }
      }
      for (int j0 = 0; j0 < cnt; j0 += 16) {
        int jj = j0 + l;
        unsigned p = (jj < cnt) ? rec[bs + jj] : 0xFFFFFFFFu;
        bool mine = (p != 0xFFFFFFFFu) && (int)((p >> 20) & 127) == want;
        float ex = 0.f; int ty = 7;
        if (mine) {
          float ef = s_src[p & 0x1FFFF] + sdl[di];
          ef = ef >= 0.f ? ef : 0.2f * ef;
          ty = (p >> 17) & 7;
          ex = __expf(ef - mx[ty]);
        }
        #pragma unroll
        for (int tt = 0; tt < NTYPES; ++tt) {
          float v = (ty == tt) ? ex : 0.f;
          v += __shfl_xor(v, 1); v += __shfl_xor(v, 2);
          v += __shfl_xor(v, 4); v += __shfl_xor(v, 8);
          sm[tt] += v;
        }
      }
      float rsm[NTYPES];
      #pragma unroll
      for (int tt = 0; tt < NTYPES; ++tt) rsm[tt] = sm[tt] > 0.f ? 1.f / sm[tt] : 0.f;
      float acc[8] = {0.f, 0.f, 0.f, 0.f, 0.f, 0.f, 0.f, 0.f};
      for (int j0 = 0; j0 < cnt; j0 += 16) {
        int jj = j0 + l;
        unsigned p = (jj < cnt) ? rec[bs + jj] : 0xFFFFFFFFu;
        bool mine = (p != 0xFFFFFFFFu) && (int)((p >> 20) & 127) == want;
        float al = 0.f;
        if (mine) {
          float ef = s_src[p & 0x1FFFF] + sdl[di];
          ef = ef >= 0.f ? ef : 0.2f * ef;
          int ty = (p >> 17) & 7;
          al = __expf(ef - mx[ty]) * rsm[ty];
        }
        unsigned pv = mine ? p : 0xFFFFFFFFu;
        for (int jj2 = 0; jj2 < 16; ++jj2) {
          unsigned pp = __shfl(pv, gb + jj2);
          float aa = __shfl(al, gb + jj2);
          if (pp != 0xFFFFFFFFu) {
            half8 x = *(const half8*)(nfl + (size_t)(pp & 0x1FFFF) * 128 + l * 8);
            #pragma unroll
            for (int kk = 0; kk < 8; ++kk) acc[kk] = fmaf(aa, (float)x[kk], acc[kk]);
          }
        }
      }
      half8 hv;
      #pragma unroll
      for (int kk = 0; kk < 8; ++kk) hv[kk] = (_Float16)acc[kk];
      *(half8*)(h + (size_t)(d0 + di) * 128 + l * 8) = hv;
    }
  }
}

// out = relu(b + nh16 @ Wo1^T + h @ Wo2^T); all-f16 A reads, W in LDS,
// batched loads (no explicit dbuf — keep VGPR low for occupancy).
__global__ __launch_bounds__(256, 6) void k_gemmO(
    const _Float16* __restrict__ nh16, const _Float16* __restrict__ hbuf,
    const float* __restrict__ Wout, const float* __restrict__ bias,
    float* __restrict__ out, int n)
{
  __shared__ _Float16 w1[64 * 128], w2[64 * 128];  // 32 KB
  const int t = threadIdx.x, lane = t & 63, wv = t >> 6;
  const int r16 = lane & 15, g = lane >> 4;
  const int jhalf = blockIdx.x & 1;
  stage_f32(w1, Wout, 64, 64, 0,  jhalf * 64, 1 << 30, t);
  stage_f32(w2, Wout, 64, 64, 32, jhalf * 64, 1 << 30, t);
  float bv[4];
  #pragma unroll
  for (int nf = 0; nf < 4; ++nf) bv[nf] = bias[jhalf * 64 + nf * 16 + r16];
  __syncthreads();
  const int nchunk = (n + 63) >> 6;
  const int gstride = gridDim.x >> 1;
  for (int c = blockIdx.x >> 1; c < nchunk; c += gstride) {
    const int arow = (c << 6) + wv * 16 + r16;
    const bool ok = arow < n;
    half8 c1[4], c2[4];
    #pragma unroll
    for (int s = 0; s < 4; ++s) {
      c1[s] = ok ? *(const half8*)(nh16 + (size_t)arow * 128 + s * 32 + g * 8) : (half8){};
      c2[s] = ok ? *(const half8*)(hbuf + (size_t)arow * 128 + s * 32 + g * 8) : (half8){};
    }
    float4v acc[4];
    #pragma unroll
    for (int nf = 0; nf < 4; ++nf) acc[nf] = (float4v){0.f, 0.f, 0.f, 0.f};
    #pragma unroll
    for (int s = 0; s < 4; ++s) {
      #pragma unroll
      for (int nf = 0; nf < 4; ++nf) {
        acc[nf] = __builtin_amdgcn_mfma_f32_16x16x32_f16(c1[s], frag_ld(w1, nf * 16 + r16, s * 32 + g * 8), acc[nf], 0, 0, 0);
        acc[nf] = __builtin_amdgcn_mfma_f32_16x16x32_f16(c2[s], frag_ld(w2, nf * 16 + r16, s * 32 + g * 8), acc[nf], 0, 0, 0);
      }
    }
    #pragma unroll
    for (int rr = 0; rr < 4; ++rr) {
      int node = (c << 6) + wv * 16 + g * 4 + rr;
      if (node >= n) continue;
      #pragma unroll
      for (int nf = 0; nf < 4; ++nf)
        out[(size_t)node * 128 + jhalf * 64 + nf * 16 + r16] = fmaxf(acc[nf][rr] + bv[nf], 0.f);
    }
  }
}

extern "C" void kernel_launch(void* const* d_in, const int* in_sizes, int n_in,
                              void* d_out, int out_size, void* d_ws, size_t ws_size,
                              hipStream_t stream) {
  const float* nh     = (const float*)d_in[0];
  const int*   edge_y = (const int*)d_in[1];
  const int*   ei     = (const int*)d_in[2];
  const float* W_nf   = (const float*)d_in[3];
  const float* W_attn = (const float*)d_in[4];
  const float* W_out  = (const float*)d_in[5];
  const float* b_out  = (const float*)d_in[6];
  float* out = (float*)d_out;
  const int n = in_sizes[0] / 128;
  const int e = in_sizes[1];
  const int nbk  = (n + BKDST - 1) >> BKSH;  // coarse buckets of 128 dsts
  const int nblk = (e + EPB - 1) / EPB;      // hist/scatter blocks (245)
  const int ncnt = nbk * nblk;               // ~191K
  const int nb2  = (ncnt + 1023) / 1024;     // ~188 <= 256
  const int nsb  = (n + SUBD - 1) / SUBD;    // agg2 sub-buckets (3125)

  // workspace layout
  _Float16* nfl_h = (_Float16*)d_ws;                   // n*128 f16
  _Float16* nh16  = nfl_h + (size_t)n * 128;           // n*128 f16
  _Float16* h_h   = nh16 + (size_t)n * 128;            // n*128 f16
  float* s_src = (float*)(h_h + (size_t)n * 128);      // n
  float* s_dst = s_src + n;                            // n
  int*   cnt   = (int*)(s_dst + n);                    // nbk*nblk
  int*   bsum  = cnt + ncnt;                           // 256
  int*   boff  = bsum + 256;                           // 256
  unsigned* rec = (unsigned*)(boff + 256);             // e

  // 1) nfl = nh@Wnf^T ; nh16 = (f16)nh
  k_gemm0<<<1280, 256, 0, stream>>>(nh, W_nf, nfl_h, nh16, n);
  // 2) s_src/s_dst = nfl16 @ a_src/a_dst
  k_attn<<<(n + 15) / 16, 256, 0, stream>>>(nfl_h, W_attn, s_src, s_dst, n);
  // 3) coarse-bucket histogram + scan (in-place)
  k_hist<<<nblk, 256, 0, stream>>>(ei + e, cnt, e, nbk, nblk);
  k_scan1<<<nb2, 256, 0, stream>>>(cnt, cnt, bsum, ncnt);
  k_scan2<<<1, 256, 0, stream>>>(bsum, boff, nb2);
  k_scan3<<<(ncnt + 255) / 256, 256, 0, stream>>>(cnt, boff, ncnt);
  // 4) bucket-grouped scatter (4B payload)
  k_scatter2<<<nblk, 256, 0, stream>>>(ei, edge_y, cnt, rec, e, nbk, nblk);
  // 5) per-sub-bucket LDS CSR + softmax + aggregate -> h (f16)
  k_agg2<<<nsb, 256, 0, stream>>>(rec, cnt, s_src, s_dst, nfl_h, h_h, n, e, nbk, nblk);
  // 6) out = relu(b + nh16@Wo1^T + h@Wo2^T)
  k_gemmO<<<1280, 256, 0, stream>>>(nh16, h_h, W_out, b_out, out, n);
}

// Round 15
// 164.854 us; speedup vs baseline: 1.4543x; 1.4543x over previous
//
#include <hip/hip_runtime.h>

#define NTYPES 5
#define EPB 4096      // edges per hist/scatter block -> 245 blocks at e=1M
#define BKSH 7        // coarse scatter bucket = 128 dsts (nbk=782)
#define BKDST 128
#define SUBD 32       // agg2 sub-bucket = 32 dsts
#define CAP 1024      // max records per 32-dst sub-bucket in LDS (avg 320)

typedef _Float16 half8 __attribute__((ext_vector_type(8)));
typedef _Float16 half4v __attribute__((ext_vector_type(4)));
typedef float float4v __attribute__((ext_vector_type(4)));

// stage rows x 128 f32 tile -> f16 LDS, row stride 256 B, swizzle byte ^= (row&7)<<4
__device__ __forceinline__ void stage_f32(
    _Float16* lds, const float* __restrict__ g, int rows, int stride4, int off4,
    int grow0, int nmax, int t)
{
  const float4* g4 = (const float4*)g;
  for (int i = t; i < rows * 32; i += 256) {
    int row = i >> 5, q = i & 31;
    float4 v = make_float4(0.f, 0.f, 0.f, 0.f);
    int gr = grow0 + row;
    if (gr < nmax) v = g4[(size_t)gr * stride4 + off4 + q];
    half4v hv = { (_Float16)v.x, (_Float16)v.y, (_Float16)v.z, (_Float16)v.w };
    int byte = row * 256 + ((q * 8) ^ ((row & 7) << 4));
    *(half4v*)((char*)lds + byte) = hv;
  }
}

__device__ __forceinline__ half8 frag_ld(const _Float16* lds, int row, int khw) {
  int byte = row * 256 + ((khw * 2) ^ ((row & 7) << 4));
  return *(const half8*)((const char*)lds + byte);
}

__device__ __forceinline__ half8 cvt8(float4 v0, float4 v1) {
  half8 a;
  a[0] = (_Float16)v0.x; a[1] = (_Float16)v0.y; a[2] = (_Float16)v0.z; a[3] = (_Float16)v0.w;
  a[4] = (_Float16)v1.x; a[5] = (_Float16)v1.y; a[6] = (_Float16)v1.z; a[7] = (_Float16)v1.w;
  return a;
}

// nfl(f16) = nh @ Wnf^T ; nh16 = (f16)nh ; s_src/s_dst = nfl @ a_src/a_dst
// W in LDS (32 KB), A direct from global (batched loads, no prefetch dbuf).
__global__ __launch_bounds__(256) void k_gemm0(
    const float* __restrict__ nh, const float* __restrict__ Wnf,
    const float* __restrict__ Wattn,
    float* __restrict__ s_src, float* __restrict__ s_dst,
    _Float16* __restrict__ nfl, _Float16* __restrict__ nh16, int n)
{
  __shared__ _Float16 wh[128 * 128];
  const int t = threadIdx.x, lane = t & 63, wv = t >> 6;
  const int r16 = lane & 15, g = lane >> 4;
  stage_f32(wh, Wnf, 128, 32, 0, 0, 1 << 30, t);
  float asrc[8], adst[8];
  #pragma unroll
  for (int nf = 0; nf < 8; ++nf) {
    asrc[nf] = Wattn[nf * 16 + r16];
    adst[nf] = Wattn[128 + nf * 16 + r16];
  }
  __syncthreads();
  const int nchunk = (n + 63) >> 6;
  for (int c = blockIdx.x; c < nchunk; c += gridDim.x) {
    const int base = c << 6;
    const int arow = base + wv * 16 + r16;
    const bool ok = arow < n;
    const float4* nh4 = (const float4*)(nh + (size_t)arow * 128);
    const float4 z = make_float4(0.f, 0.f, 0.f, 0.f);
    float4 av[8];
    #pragma unroll
    for (int s = 0; s < 4; ++s) {
      av[2 * s]     = ok ? nh4[s * 8 + g * 2]     : z;
      av[2 * s + 1] = ok ? nh4[s * 8 + g * 2 + 1] : z;
    }
    float4v acc[8];
    #pragma unroll
    for (int nf = 0; nf < 8; ++nf) acc[nf] = (float4v){0.f, 0.f, 0.f, 0.f};
    #pragma unroll
    for (int s = 0; s < 4; ++s) {
      half8 a = cvt8(av[2 * s], av[2 * s + 1]);
      if (ok) *(half8*)(nh16 + (size_t)arow * 128 + s * 32 + g * 8) = a;
      #pragma unroll
      for (int nf = 0; nf < 8; ++nf)
        acc[nf] = __builtin_amdgcn_mfma_f32_16x16x32_f16(a, frag_ld(wh, nf * 16 + r16, s * 32 + g * 8), acc[nf], 0, 0, 0);
    }
    #pragma unroll
    for (int rr = 0; rr < 4; ++rr) {
      int node = base + wv * 16 + g * 4 + rr;
      if (node >= n) continue;
      size_t ro = (size_t)node * 128;
      #pragma unroll
      for (int nf = 0; nf < 8; ++nf) nfl[ro + nf * 16 + r16] = (_Float16)acc[nf][rr];
    }
    float ss[4] = {0.f, 0.f, 0.f, 0.f}, sd[4] = {0.f, 0.f, 0.f, 0.f};
    #pragma unroll
    for (int nf = 0; nf < 8; ++nf)
      #pragma unroll
      for (int rr = 0; rr < 4; ++rr) {
        ss[rr] = fmaf(acc[nf][rr], asrc[nf], ss[rr]);
        sd[rr] = fmaf(acc[nf][rr], adst[nf], sd[rr]);
      }
    #pragma unroll
    for (int m = 1; m <= 8; m <<= 1)
      #pragma unroll
      for (int rr = 0; rr < 4; ++rr) {
        ss[rr] += __shfl_xor(ss[rr], m);
        sd[rr] += __shfl_xor(sd[rr], m);
      }
    if (r16 == 0) {
      #pragma unroll
      for (int rr = 0; rr < 4; ++rr) {
        int node = base + wv * 16 + g * 4 + rr;
        if (node < n) { s_src[node] = ss[rr]; s_dst[node] = sd[rr]; }
      }
    }
  }
}

// per-block coarse-bucket histogram (bucket = dst >> BKSH), LDS atomics only
__global__ __launch_bounds__(256) void k_hist(
    const int* __restrict__ dsts, int* __restrict__ cnt, int e, int nbk, int nblk)
{
  __shared__ int hist[1024];
  const int t = threadIdx.x, b = blockIdx.x;
  for (int k = t; k < nbk; k += 256) hist[k] = 0;
  __syncthreads();
  const int i0 = b * EPB;
  const int iend = min(i0 + EPB, e);
  for (int i = i0 + t; i < iend; i += 256)
    atomicAdd(&hist[dsts[i] >> BKSH], 1);
  __syncthreads();
  for (int k = t; k < nbk; k += 256) cnt[k * nblk + b] = hist[k];
}

// ---- exclusive scan (in-place capable), 1024 elems per block ----
__global__ __launch_bounds__(256) void k_scan1(
    const int* __restrict__ deg, int* __restrict__ base, int* __restrict__ bsum, int n)
{
  __shared__ int ws[4];
  int t = threadIdx.x;
  int g0 = blockIdx.x * 1024 + t * 4;
  int4 v = make_int4(0, 0, 0, 0);
  if (g0 + 3 < n) v = *(const int4*)(deg + g0);
  else {
    if (g0     < n) v.x = deg[g0];
    if (g0 + 1 < n) v.y = deg[g0 + 1];
    if (g0 + 2 < n) v.z = deg[g0 + 2];
    if (g0 + 3 < n) v.w = deg[g0 + 3];
  }
  int s = v.x + v.y + v.z + v.w;
  int inc = s;
  #pragma unroll
  for (int d = 1; d < 64; d <<= 1) {
    int o = __shfl_up(inc, d);
    if ((t & 63) >= d) inc += o;
  }
  int wid = t >> 6;
  if ((t & 63) == 63) ws[wid] = inc;
  __syncthreads();
  int woff = 0;
  for (int w = 0; w < wid; ++w) woff += ws[w];
  int exc = woff + inc - s;
  if (g0 + 3 < n) {
    *(int4*)(base + g0) = make_int4(exc, exc + v.x, exc + v.x + v.y, exc + v.x + v.y + v.z);
  } else {
    if (g0     < n) base[g0]     = exc;
    if (g0 + 1 < n) base[g0 + 1] = exc + v.x;
    if (g0 + 2 < n) base[g0 + 2] = exc + v.x + v.y;
  }
  if (t == 255) bsum[blockIdx.x] = woff + inc;
}

__global__ __launch_bounds__(256) void k_scan2(
    const int* __restrict__ bsum, int* __restrict__ boff, int nb)
{
  __shared__ int ws[4];
  int t = threadIdx.x;
  int x = t < nb ? bsum[t] : 0;
  int inc = x;
  #pragma unroll
  for (int d = 1; d < 64; d <<= 1) {
    int o = __shfl_up(inc, d);
    if ((t & 63) >= d) inc += o;
  }
  int wid = t >> 6;
  if ((t & 63) == 63) ws[wid] = inc;
  __syncthreads();
  int woff = 0;
  for (int w = 0; w < wid; ++w) woff += ws[w];
  if (t < nb) boff[t] = woff + inc - x;
}

__global__ __launch_bounds__(256) void k_scan3(
    int* __restrict__ base, const int* __restrict__ boff, int n)
{
  int i = blockIdx.x * 256 + threadIdx.x;
  if (i < n) base[i] += boff[i >> 10];
}

// bucket-grouped scatter: payload = src | ty<<17 | (d&127)<<20, LDS cursors
__global__ __launch_bounds__(256) void k_scatter2(
    const int* __restrict__ ei, const int* __restrict__ ey,
    const int* __restrict__ cnt_s, unsigned* __restrict__ rec,
    int e, int nbk, int nblk)
{
  __shared__ int cur[1024];
  const int t = threadIdx.x, b = blockIdx.x;
  for (int k = t; k < nbk; k += 256) cur[k] = cnt_s[k * nblk + b];
  __syncthreads();
  const int i0 = b * EPB;
  const int iend = min(i0 + EPB, e);
  for (int i = i0 + t; i < iend; i += 256) {
    int s = ei[i], d = ei[e + i], ty = ey[i];
    int pos = atomicAdd(&cur[d >> BKSH], 1);
    rec[pos] = (unsigned)s | ((unsigned)ty << 17) | ((unsigned)(d & (BKDST - 1)) << 20);
  }
}

// one block per 32-dst SUB-bucket: filter coarse-bucket records, LDS CSR,
// per-dst softmax + gather aggregate -> h (f16)
__global__ __launch_bounds__(256) void k_agg2(
    const unsigned* __restrict__ rec, const int* __restrict__ cnt_s,
    const float* __restrict__ s_src, const float* __restrict__ s_dst,
    const _Float16* __restrict__ nfl, _Float16* __restrict__ h,
    int n, int e, int nbk, int nblk)
{
  __shared__ unsigned ord[CAP];
  __shared__ float efl[CAP];
  __shared__ int dcnt[SUBD];
  __shared__ int dbase[SUBD + 1];
  __shared__ float sdl[SUBD];
  const int t = threadIdx.x;
  const int sb = blockIdx.x;       // sub-bucket id
  const int d0 = sb << 5;          // first dst
  const int ndst = min(SUBD, n - d0);
  const int k = sb >> 2;           // coarse bucket (128 dsts)
  const int sub = sb & 3;
  const int bs = cnt_s[k * nblk];
  const int be = (k + 1 < nbk) ? cnt_s[(k + 1) * nblk] : e;
  const int cnt = be - bs;
  if (t < SUBD) {
    dcnt[t] = 0;
    if (t < ndst) sdl[t] = s_dst[d0 + t];
  }
  __syncthreads();
  const int g = t >> 4, l = t & 15;

  // count pass (filtered to this sub-bucket)
  for (int i = t; i < cnt; i += 256) {
    int dl = (rec[bs + i] >> 20) & 127;
    if ((dl >> 5) == sub) atomicAdd(&dcnt[dl & 31], 1);
  }
  __syncthreads();
  if (t < SUBD) {  // single-wave exclusive scan dcnt -> dbase (+cursor seed)
    int v = dcnt[t];
    int inc = v;
    #pragma unroll
    for (int dd = 1; dd < SUBD; dd <<= 1) {
      int o = __shfl_up(inc, dd);
      if (t >= dd) inc += o;
    }
    dbase[t] = inc - v;
    dcnt[t]  = inc - v;
    if (t == SUBD - 1) dbase[SUBD] = inc;
  }
  __syncthreads();
  const int total = dbase[SUBD];

  if (total <= CAP) {
    for (int i = t; i < cnt; i += 256) {
      unsigned p = rec[bs + i];
      int dl = (p >> 20) & 127;
      if ((dl >> 5) == sub) {
        int pos = atomicAdd(&dcnt[dl & 31], 1);
        ord[pos] = p;
      }
    }
    __syncthreads();
    for (int i = t; i < total; i += 256) {
      unsigned p = ord[i];
      float ef = s_src[p & 0x1FFFF] + sdl[(p >> 20) & 31];
      efl[i] = ef >= 0.f ? ef : 0.2f * ef;
    }
    __syncthreads();
    for (int di = g; di < ndst; di += 16) {
      int s0 = dbase[di], deg = dbase[di + 1] - s0;
      float acc[8] = {0.f, 0.f, 0.f, 0.f, 0.f, 0.f, 0.f, 0.f};
      if (deg > 0) {
        float mx[NTYPES];
        #pragma unroll
        for (int tt = 0; tt < NTYPES; ++tt) mx[tt] = -1e30f;
        for (int j0 = 0; j0 < deg; j0 += 16) {
          int jj = j0 + l;
          bool ok = jj < deg;
          float ef = ok ? efl[s0 + jj] : -1e30f;
          int ty = ok ? (int)((ord[s0 + jj] >> 17) & 7) : 7;
          #pragma unroll
          for (int tt = 0; tt < NTYPES; ++tt) {
            float v = (ty == tt) ? ef : -1e30f;
            v = fmaxf(v, __shfl_xor(v, 1)); v = fmaxf(v, __shfl_xor(v, 2));
            v = fmaxf(v, __shfl_xor(v, 4)); v = fmaxf(v, __shfl_xor(v, 8));
            mx[tt] = fmaxf(mx[tt], v);
          }
        }
        float sm[NTYPES];
        #pragma unroll
        for (int tt = 0; tt < NTYPES; ++tt) sm[tt] = 0.f;
        for (int j0 = 0; j0 < deg; j0 += 16) {
          int jj = j0 + l;
          bool ok = jj < deg;
          int ty = ok ? (int)((ord[s0 + jj] >> 17) & 7) : 7;
          float ex = ok ? __expf(efl[s0 + jj] - mx[ty]) : 0.f;
          if (ok) efl[s0 + jj] = ex;
          #pragma unroll
          for (int tt = 0; tt < NTYPES; ++tt) {
            float v = (ty == tt) ? ex : 0.f;
            v += __shfl_xor(v, 1); v += __shfl_xor(v, 2);
            v += __shfl_xor(v, 4); v += __shfl_xor(v, 8);
            sm[tt] += v;
          }
        }
        float rsm[NTYPES];
        #pragma unroll
        for (int tt = 0; tt < NTYPES; ++tt) rsm[tt] = sm[tt] > 0.f ? 1.f / sm[tt] : 0.f;
        int j = 0;
        for (; j + 4 <= deg; j += 4) {
          unsigned p0 = ord[s0 + j],     p1 = ord[s0 + j + 1];
          unsigned p2 = ord[s0 + j + 2], p3 = ord[s0 + j + 3];
          float a0 = efl[s0 + j]     * rsm[(p0 >> 17) & 7];
          float a1 = efl[s0 + j + 1] * rsm[(p1 >> 17) & 7];
          float a2 = efl[s0 + j + 2] * rsm[(p2 >> 17) & 7];
          float a3 = efl[s0 + j + 3] * rsm[(p3 >> 17) & 7];
          half8 x0 = *(const half8*)(nfl + (size_t)(p0 & 0x1FFFF) * 128 + l * 8);
          half8 x1 = *(const half8*)(nfl + (size_t)(p1 & 0x1FFFF) * 128 + l * 8);
          half8 x2 = *(const half8*)(nfl + (size_t)(p2 & 0x1FFFF) * 128 + l * 8);
          half8 x3 = *(const half8*)(nfl + (size_t)(p3 & 0x1FFFF) * 128 + l * 8);
          #pragma unroll
          for (int kk = 0; kk < 8; ++kk) acc[kk] = fmaf(a0, (float)x0[kk], acc[kk]);
          #pragma unroll
          for (int kk = 0; kk < 8; ++kk) acc[kk] = fmaf(a1, (float)x1[kk], acc[kk]);
          #pragma unroll
          for (int kk = 0; kk < 8; ++kk) acc[kk] = fmaf(a2, (float)x2[kk], acc[kk]);
          #pragma unroll
          for (int kk = 0; kk < 8; ++kk) acc[kk] = fmaf(a3, (float)x3[kk], acc[kk]);
        }
        for (; j < deg; ++j) {
          unsigned p0 = ord[s0 + j];
          float a0 = efl[s0 + j] * rsm[(p0 >> 17) & 7];
          half8 x0 = *(const half8*)(nfl + (size_t)(p0 & 0x1FFFF) * 128 + l * 8);
          #pragma unroll
          for (int kk = 0; kk < 8; ++kk) acc[kk] = fmaf(a0, (float)x0[kk], acc[kk]);
        }
      }
      half8 hv;
      #pragma unroll
      for (int kk = 0; kk < 8; ++kk) hv[kk] = (_Float16)acc[kk];
      *(half8*)(h + (size_t)(d0 + di) * 128 + l * 8) = hv;
    }
  } else {
    // fallback (sub-bucket overflow — not expected): stream global coarse range
    const int gb = (t & 63) & 48;
    for (int di = g; di < ndst; di += 16) {
      const int want = sub * SUBD + di;
      float mx[NTYPES], sm[NTYPES];
      #pragma unroll
      for (int tt = 0; tt < NTYPES; ++tt) { mx[tt] = -1e30f; sm[tt] = 0.f; }
      for (int j0 = 0; j0 < cnt; j0 += 16) {
        int jj = j0 + l;
        unsigned p = (jj < cnt) ? rec[bs + jj] : 0xFFFFFFFFu;
        bool mine = (p != 0xFFFFFFFFu) && (int)((p >> 20) & 127) == want;
        float ef = -1e30f; int ty = 7;
        if (mine) {
          ef = s_src[p & 0x1FFFF] + sdl[di];
          ef = ef >= 0.f ? ef : 0.2f * ef;
          ty = (p >> 17) & 7;
        }
        #pragma unroll
        for (int tt = 0; tt < NTYPES; ++tt) {
          float v = (mine && ty == tt) ? ef : -1e30f;
          v = fmaxf(v, __shfl_xor(v, 1)); v = fmaxf(v, __shfl_xor(v, 2));
          v = fmaxf(v, __shfl_xor(v, 4)); v = fmaxf(v, __shfl_xor(v, 8));
          mx[tt] = fmaxf(mx[tt], v);
        }
      }
      for (int j0 = 0; j0 < cnt; j0 += 16) {
        int jj = j0 + l;
        unsigned p = (jj < cnt) ? rec[bs + jj] : 0xFFFFFFFFu;
        bool mine = (p != 0xFFFFFFFFu) && (int)((p >> 20) & 127) == want;
        float ex = 0.f; int ty = 7;
        if (mine) {
          float ef = s_src[p & 0x1FFFF] + sdl[di];
          ef = ef >= 0.f ? ef : 0.2f * ef;
          ty = (p >> 17) & 7;
          ex = __expf(ef - mx[ty]);
        }
        #pragma unroll
        for (int tt = 0; tt < NTYPES; ++tt) {
          float v = (ty == tt) ? ex : 0.f;
          v += __shfl_xor(v, 1); v += __shfl_xor(v, 2);
          v += __shfl_xor(v, 4); v += __shfl_xor(v, 8);
          sm[tt] += v;
        }
      }
      float rsm[NTYPES];
      #pragma unroll
      for (int tt = 0; tt < NTYPES; ++tt) rsm[tt] = sm[tt] > 0.f ? 1.f / sm[tt] : 0.f;
      float acc[8] = {0.f, 0.f, 0.f, 0.f, 0.f, 0.f, 0.f, 0.f};
      for (int j0 = 0; j0 < cnt; j0 += 16) {
        int jj = j0 + l;
        unsigned p = (jj < cnt) ? rec[bs + jj] : 0xFFFFFFFFu;
        bool mine = (p != 0xFFFFFFFFu) && (int)((p >> 20) & 127) == want;
        float al = 0.f;
        if (mine) {
          float ef = s_src[p & 0x1FFFF] + sdl[di];
          ef = ef >= 0.f ? ef : 0.2f * ef;
          int ty = (p >> 17) & 7;
          al = __expf(ef - mx[ty]) * rsm[ty];
        }
        unsigned pv = mine ? p : 0xFFFFFFFFu;
        for (int jj2 = 0; jj2 < 16; ++jj2) {
          unsigned pp = __shfl(pv, gb + jj2);
          float aa = __shfl(al, gb + jj2);
          if (pp != 0xFFFFFFFFu) {
            half8 x = *(const half8*)(nfl + (size_t)(pp & 0x1FFFF) * 128 + l * 8);
            #pragma unroll
            for (int kk = 0; kk < 8; ++kk) acc[kk] = fmaf(aa, (float)x[kk], acc[kk]);
          }
        }
      }
      half8 hv;
      #pragma unroll
      for (int kk = 0; kk < 8; ++kk) hv[kk] = (_Float16)acc[kk];
      *(half8*)(h + (size_t)(d0 + di) * 128 + l * 8) = hv;
    }
  }
}

// out = relu(b + nh16 @ Wo1^T + h @ Wo2^T); all-f16 A reads, W in LDS,
// persistent grid, register double-buffered A-pairs, no per-chunk barriers.
__global__ __launch_bounds__(256) void k_gemmO(
    const _Float16* __restrict__ nh16, const _Float16* __restrict__ hbuf,
    const float* __restrict__ Wout, const float* __restrict__ bias,
    float* __restrict__ out, int n)
{
  __shared__ _Float16 w1[64 * 128], w2[64 * 128];  // 32 KB
  const int t = threadIdx.x, lane = t & 63, wv = t >> 6;
  const int r16 = lane & 15, g = lane >> 4;
  const int jhalf = blockIdx.x & 1;
  stage_f32(w1, Wout, 64, 64, 0,  jhalf * 64, 1 << 30, t);
  stage_f32(w2, Wout, 64, 64, 32, jhalf * 64, 1 << 30, t);
  float bv[4];
  #pragma unroll
  for (int nf = 0; nf < 4; ++nf) bv[nf] = bias[jhalf * 64 + nf * 16 + r16];
  __syncthreads();
  const int nchunk = (n + 63) >> 6;
  const int gstride = gridDim.x >> 1;
  int c = blockIdx.x >> 1;
  half8 c1[4], c2[4];
  if (c < nchunk) {
    int arow = (c << 6) + wv * 16 + r16;
    bool ok = arow < n;
    #pragma unroll
    for (int s = 0; s < 4; ++s) {
      c1[s] = ok ? *(const half8*)(nh16 + (size_t)arow * 128 + s * 32 + g * 8) : (half8){};
      c2[s] = ok ? *(const half8*)(hbuf + (size_t)arow * 128 + s * 32 + g * 8) : (half8){};
    }
  }
  for (; c < nchunk; c += gstride) {
    const int base = c << 6;
    int cn = c + gstride;
    half8 n1[4] = {}, n2[4] = {};
    if (cn < nchunk) {
      int nrow = (cn << 6) + wv * 16 + r16;
      bool ok = nrow < n;
      #pragma unroll
      for (int s = 0; s < 4; ++s) {
        n1[s] = ok ? *(const half8*)(nh16 + (size_t)nrow * 128 + s * 32 + g * 8) : (half8){};
        n2[s] = ok ? *(const half8*)(hbuf + (size_t)nrow * 128 + s * 32 + g * 8) : (half8){};
      }
    }
    float4v acc[4];
    #pragma unroll
    for (int nf = 0; nf < 4; ++nf) acc[nf] = (float4v){0.f, 0.f, 0.f, 0.f};
    #pragma unroll
    for (int s = 0; s < 4; ++s) {
      #pragma unroll
      for (int nf = 0; nf < 4; ++nf) {
        acc[nf] = __builtin_amdgcn_mfma_f32_16x16x32_f16(c1[s], frag_ld(w1, nf * 16 + r16, s * 32 + g * 8), acc[nf], 0, 0, 0);
        acc[nf] = __builtin_amdgcn_mfma_f32_16x16x32_f16(c2[s], frag_ld(w2, nf * 16 + r16, s * 32 + g * 8), acc[nf], 0, 0, 0);
      }
    }
    #pragma unroll
    for (int rr = 0; rr < 4; ++rr) {
      int node = base + wv * 16 + g * 4 + rr;
      if (node >= n) continue;
      #pragma unroll
      for (int nf = 0; nf < 4; ++nf)
        out[(size_t)node * 128 + jhalf * 64 + nf * 16 + r16] = fmaxf(acc[nf][rr] + bv[nf], 0.f);
    }
    #pragma unroll
    for (int s = 0; s < 4; ++s) { c1[s] = n1[s]; c2[s] = n2[s]; }
  }
}

extern "C" void kernel_launch(void* const* d_in, const int* in_sizes, int n_in,
                              void* d_out, int out_size, void* d_ws, size_t ws_size,
                              hipStream_t stream) {
  const float* nh     = (const float*)d_in[0];
  const int*   edge_y = (const int*)d_in[1];
  const int*   ei     = (const int*)d_in[2];
  const float* W_nf   = (const float*)d_in[3];
  const float* W_attn = (const float*)d_in[4];
  const float* W_out  = (const float*)d_in[5];
  const float* b_out  = (const float*)d_in[6];
  float* out = (float*)d_out;
  const int n = in_sizes[0] / 128;
  const int e = in_sizes[1];
  const int nbk  = (n + BKDST - 1) >> BKSH;  // coarse buckets of 128 dsts
  const int nblk = (e + EPB - 1) / EPB;      // hist/scatter blocks (245)
  const int ncnt = nbk * nblk;               // ~191K
  const int nb2  = (ncnt + 1023) / 1024;     // ~188 <= 256
  const int nsb  = (n + SUBD - 1) / SUBD;    // agg2 sub-buckets (3125)

  // workspace layout
  _Float16* nfl_h = (_Float16*)d_ws;                   // n*128 f16
  _Float16* nh16  = nfl_h + (size_t)n * 128;           // n*128 f16
  _Float16* h_h   = nh16 + (size_t)n * 128;            // n*128 f16
  float* s_src = (float*)(h_h + (size_t)n * 128);      // n
  float* s_dst = s_src + n;                            // n
  int*   cnt   = (int*)(s_dst + n);                    // nbk*nblk
  int*   bsum  = cnt + ncnt;                           // 256
  int*   boff  = bsum + 256;                           // 256
  unsigned* rec = (unsigned*)(boff + 256);             // e

  // 1) nfl = nh@Wnf^T ; nh16 = (f16)nh ; s_src/s_dst
  k_gemm0<<<1280, 256, 0, stream>>>(nh, W_nf, W_attn, s_src, s_dst, nfl_h, nh16, n);
  // 2) coarse-bucket histogram + scan (in-place)
  k_hist<<<nblk, 256, 0, stream>>>(ei + e, cnt, e, nbk, nblk);
  k_scan1<<<nb2, 256, 0, stream>>>(cnt, cnt, bsum, ncnt);
  k_scan2<<<1, 256, 0, stream>>>(bsum, boff, nb2);
  k_scan3<<<(ncnt + 255) / 256, 256, 0, stream>>>(cnt, boff, ncnt);
  // 3) bucket-grouped scatter (4B payload)
  k_scatter2<<<nblk, 256, 0, stream>>>(ei, edge_y, cnt, rec, e, nbk, nblk);
  // 4) per-sub-bucket LDS CSR + softmax + aggregate -> h (f16)
  k_agg2<<<nsb, 256, 0, stream>>>(rec, cnt, s_src, s_dst, nfl_h, h_h, n, e, nbk, nblk);
  // 5) out = relu(b + nh16@Wo1^T + h@Wo2^T)
  k_gemmO<<<1280, 256, 0, stream>>>(nh16, h_h, W_out, b_out, out, n);
}